// Round 6
// baseline (593.471 us; speedup 1.0000x reference)
//
#include <hip/hip_runtime.h>
#include <hip/hip_bf16.h>

#define N_NODES   20000
#define N_EDGES   320000
#define DIM       256
#define N_GRAPHS  64
#define N_CLASSES 10
#define CHUNK     (N_NODES * 128)          // one feature-chunk of fp8 H (2.56 MB)
// CSR holds edges + 1 self-loop per node, each row padded to a multiple of 8
#define CSR_CAP   (N_EDGES + 9 * N_NODES)

typedef short  bf16x8 __attribute__((ext_vector_type(8)));
typedef float  f32x4  __attribute__((ext_vector_type(4)));
typedef float  f32x2  __attribute__((ext_vector_type(2)));

__device__ __forceinline__ float b2f(ushort u) {
    return __uint_as_float(((unsigned)u) << 16);
}
__device__ __forceinline__ ushort f2b(float f) {
    unsigned u = __float_as_uint(f);
    u += 0x7FFF + ((u >> 16) & 1);   // round-to-nearest-even
    return (ushort)(u >> 16);
}
// float -> fp8 e4m3 (OCP on gfx950), single value in byte 0
__device__ __forceinline__ unsigned char f2fp8(float f) {
    return (unsigned char)__builtin_amdgcn_cvt_pk_fp8_f32(f, f, 0, false);
}

// ---------------- setup kernels ----------------

__global__ void k_convert_x(const float* __restrict__ x, ushort* __restrict__ xb, int n4) {
    int i = blockIdx.x * blockDim.x + threadIdx.x;
    if (i >= n4) return;
    const float4 v = ((const float4*)x)[i];
    ushort4 o; o.x = f2b(v.x); o.y = f2b(v.y); o.z = f2b(v.z); o.w = f2b(v.w);
    ((ushort4*)xb)[i] = o;
}

// Wt[n*256+k] = bf16(W[k*256+n])
__global__ void k_wt(const float* __restrict__ W, ushort* __restrict__ Wt) {
    int i = blockIdx.x * blockDim.x + threadIdx.x;   // 65536
    int n = i >> 8, k = i & 255;
    Wt[i] = f2b(W[k * 256 + n]);
}

__global__ void k_deg(const int* __restrict__ dst, int* __restrict__ deg) {
    int e = blockIdx.x * 256 + threadIdx.x;
    if (e < N_EDGES) atomicAdd(&deg[dst[e]], 1);
}

__global__ void k_counts(const int* __restrict__ batch, int* __restrict__ counts) {
    int i = blockIdx.x * 256 + threadIdx.x;
    if (i < N_NODES) atomicAdd(&counts[batch[i]], 1);
}

// dinv = rsqrt(in_deg + 1) (self-loop); pdeg = (deg+1 incl self) rounded up to mult of 8
__global__ void k_dinv_pdeg(const int* __restrict__ deg, float* __restrict__ dinv,
                            int* __restrict__ pdeg) {
    int i = blockIdx.x * 256 + threadIdx.x;
    if (i < N_NODES) {
        int d = deg[i];
        dinv[i] = rsqrtf((float)d + 1.0f);
        pdeg[i] = (d + 1 + 7) & ~7;
    }
}

// single-block exclusive scan of pdeg -> row_ptr[0..n]
__global__ void k_scan(const int* __restrict__ pdeg, int* __restrict__ row_ptr, int n) {
    __shared__ int sh[1024];
    int tid = threadIdx.x;
    int off = 0;
    int nchunk = (n + 1023) >> 10;
    for (int c = 0; c < nchunk; ++c) {
        int i = (c << 10) + tid;
        int v = (i < n) ? pdeg[i] : 0;
        sh[tid] = v;
        __syncthreads();
        for (int s = 1; s < 1024; s <<= 1) {
            int t = (tid >= s) ? sh[tid - s] : 0;
            __syncthreads();
            sh[tid] += t;
            __syncthreads();
        }
        if (i < n) row_ptr[i] = off + sh[tid] - v;   // exclusive
        off += sh[1023];
        __syncthreads();
    }
    if (tid == 0) row_ptr[n] = off;
}

// packed CSR entry: src node in low 16 bits (N_NODES < 32768), bf16 weight in high 16.
// insert self-loop entry (i, dinv_i^2) -- runs before k_fill
__global__ void k_self(const int* __restrict__ row_ptr, int* __restrict__ fill,
                       const float* __restrict__ dinv, unsigned* __restrict__ csr) {
    int i = blockIdx.x * 256 + threadIdx.x;
    if (i >= N_NODES) return;
    int pos = atomicAdd(&fill[i], 1);
    csr[row_ptr[i] + pos] = ((unsigned)f2b(dinv[i] * dinv[i]) << 16) | (unsigned)i;
}

// scatter edges into padded CSR. Pad slots stay 0 (src=0, w=+0.0bf16) from memset.
__global__ void k_fill(const int* __restrict__ src, const int* __restrict__ dst,
                       const int* __restrict__ row_ptr, int* __restrict__ fill,
                       const float* __restrict__ dinv, unsigned* __restrict__ csr) {
    int e = blockIdx.x * 256 + threadIdx.x;
    if (e >= N_EDGES) return;
    int s = src[e], d = dst[e];
    int pos = atomicAdd(&fill[d], 1);
    csr[row_ptr[d] + pos] = ((unsigned)f2b(dinv[s] * dinv[d]) << 16) | (unsigned)s;
}

// ---------------- GEMM: H8 = fp8(Xb @ W), stored as 2 chunks [pass][node][128] ----------------
// Chunked layout keeps each aggregation pass's gather target at 2.56 MB < 4 MB/XCD L2.
__global__ __launch_bounds__(256) void k_gemm(const ushort* __restrict__ Xb,
                                              const ushort* __restrict__ Wt,
                                              unsigned char* __restrict__ H8) {
    int wave = threadIdx.x >> 6;
    int lane = threadIdx.x & 63;
    int m0 = blockIdx.x * 16;
    int n0 = wave * 64;
    int rl = lane & 15;
    int kq = (lane >> 4) * 8;

    const ushort* aptr = Xb + (size_t)(m0 + rl) * DIM + kq;
    f32x4 acc[4] = {};

#pragma unroll
    for (int kk = 0; kk < 8; ++kk) {
        int k0 = kk * 32;
        bf16x8 a = *(const bf16x8*)(aptr + k0);
#pragma unroll
        for (int nb = 0; nb < 4; ++nb) {
            const ushort* bptr = Wt + (size_t)(n0 + nb * 16 + rl) * DIM + k0 + kq;
            bf16x8 b = *(const bf16x8*)bptr;
            acc[nb] = __builtin_amdgcn_mfma_f32_16x16x32_bf16(a, b, acc[nb], 0, 0, 0);
        }
    }
    int crow = m0 + (lane >> 4) * 4;
#pragma unroll
    for (int nb = 0; nb < 4; ++nb) {
        int ccol = n0 + nb * 16 + rl;
        size_t base = (size_t)(ccol >> 7) * CHUNK + (ccol & 127);
#pragma unroll
        for (int r = 0; r < 4; ++r)
            H8[base + (size_t)(crow + r) * 128] = f2fp8(acc[nb][r]);
    }
}

// ---------------- aggregation: L2-resident chunk, one wave per node per pass ----------------
// Lanes: j = lane>>5 (edge slot 0/1), c = lane&31 (dword = 4 features).
// One gather instr = 2 rows x 128 B = 4 lines, all within the resident 2.56 MB chunk.
// 4 instrs (8 edges) in flight per wave; CSR packed 4 B/edge so the stream (1.7 MB)
// doesn't evict the chunk. acc[4] keeps VGPR low -> (256,8) = full occupancy.
// mode 0: relu(acc+b) ; mode 1: relu(prev+acc+b) ; mode 2: atomicAdd pooled
__global__ __launch_bounds__(256, 8) void k_agg(
    const unsigned char* __restrict__ H8, const int* __restrict__ row_ptr,
    const unsigned* __restrict__ csr, const float* __restrict__ bias,
    const ushort* __restrict__ prev, ushort* __restrict__ outb,
    float* __restrict__ pooled, const int* __restrict__ batch, int mode, int pass) {
    int wave = threadIdx.x >> 6, lane = threadIdx.x & 63;
    int i = blockIdx.x * 4 + wave;
    if (i >= N_NODES) return;
    int j = lane >> 5;           // edge slot within pair
    int c = lane & 31;           // dword within 128-B row
    const unsigned char* Hc = H8 + (size_t)pass * CHUNK + c * 4;

    float a0 = 0.f, a1 = 0.f, a2 = 0.f, a3 = 0.f;

    int e0 = row_ptr[i], e1 = row_ptr[i + 1];   // length >= 8, multiple of 8
    unsigned p0 = csr[e0 + 0 + j], p1 = csr[e0 + 2 + j];
    unsigned p2 = csr[e0 + 4 + j], p3 = csr[e0 + 6 + j];
    for (int e = e0; e < e1;) {
        unsigned c0 = p0, c1 = p1, c2 = p2, c3 = p3;
        int en = e + 8;
        if (en < e1) {
            p0 = csr[en + 0 + j]; p1 = csr[en + 2 + j];
            p2 = csr[en + 4 + j]; p3 = csr[en + 6 + j];
        }
        // 4 independent gathers, all inside the L2-resident chunk
        unsigned g0 = *(const unsigned*)(Hc + (size_t)(c0 & 0xFFFF) * 128);
        unsigned g1 = *(const unsigned*)(Hc + (size_t)(c1 & 0xFFFF) * 128);
        unsigned g2 = *(const unsigned*)(Hc + (size_t)(c2 & 0xFFFF) * 128);
        unsigned g3 = *(const unsigned*)(Hc + (size_t)(c3 & 0xFFFF) * 128);
        float w0 = b2f((ushort)(c0 >> 16)), w1 = b2f((ushort)(c1 >> 16));
        float w2 = b2f((ushort)(c2 >> 16)), w3 = b2f((ushort)(c3 >> 16));
        f32x2 lo, hi;
        lo = __builtin_amdgcn_cvt_pk_f32_fp8(g0, false);
        hi = __builtin_amdgcn_cvt_pk_f32_fp8(g0, true);
        a0 += w0 * lo[0]; a1 += w0 * lo[1]; a2 += w0 * hi[0]; a3 += w0 * hi[1];
        lo = __builtin_amdgcn_cvt_pk_f32_fp8(g1, false);
        hi = __builtin_amdgcn_cvt_pk_f32_fp8(g1, true);
        a0 += w1 * lo[0]; a1 += w1 * lo[1]; a2 += w1 * hi[0]; a3 += w1 * hi[1];
        lo = __builtin_amdgcn_cvt_pk_f32_fp8(g2, false);
        hi = __builtin_amdgcn_cvt_pk_f32_fp8(g2, true);
        a0 += w2 * lo[0]; a1 += w2 * lo[1]; a2 += w2 * hi[0]; a3 += w2 * hi[1];
        lo = __builtin_amdgcn_cvt_pk_f32_fp8(g3, false);
        hi = __builtin_amdgcn_cvt_pk_f32_fp8(g3, true);
        a0 += w3 * lo[0]; a1 += w3 * lo[1]; a2 += w3 * hi[0]; a3 += w3 * hi[1];
        e = en;
    }

    // combine the two edge-slot halves (butterfly across lane 32)
    a0 += __shfl_xor(a0, 32); a1 += __shfl_xor(a1, 32);
    a2 += __shfl_xor(a2, 32); a3 += __shfl_xor(a3, 32);

    if (j != 0) return;          // lanes 0..31 hold the full sums for features c*4..c*4+3
    int fo = pass * 128 + c * 4;
    const float4 bb = *(const float4*)(bias + fo);
    a0 += bb.x; a1 += bb.y; a2 += bb.z; a3 += bb.w;

    if (mode == 2) {
        int g = batch[i];
        float* p = pooled + (size_t)g * DIM + fo;
        atomicAdd(p + 0, a0); atomicAdd(p + 1, a1);
        atomicAdd(p + 2, a2); atomicAdd(p + 3, a3);
        return;
    }
    if (mode == 1) {
        ushort4 pv = *(const ushort4*)(prev + (size_t)i * DIM + fo);
        a0 += b2f(pv.x); a1 += b2f(pv.y); a2 += b2f(pv.z); a3 += b2f(pv.w);
    }
    ushort4 o;
    o.x = f2b(fmaxf(a0, 0.f)); o.y = f2b(fmaxf(a1, 0.f));
    o.z = f2b(fmaxf(a2, 0.f)); o.w = f2b(fmaxf(a3, 0.f));
    *(ushort4*)(outb + (size_t)i * DIM + fo) = o;
}

// ---------------- head: pooled mean -> logits -> log_softmax ----------------
__global__ void k_final(const float* __restrict__ pooled, const int* __restrict__ counts,
                        const float* __restrict__ Wc, const float* __restrict__ bc,
                        float* __restrict__ out) {
    int g = blockIdx.x, lane = threadIdx.x;   // 64 threads = 1 wave
    float inv = 1.0f / fmaxf((float)counts[g], 1.0f);
    const float4 pv = *(const float4*)(pooled + (size_t)g * DIM + lane * 4);
    float p0 = pv.x * inv, p1 = pv.y * inv, p2 = pv.z * inv, p3 = pv.w * inv;
    __shared__ float logits[N_CLASSES];
    int f = lane * 4;
    for (int c = 0; c < N_CLASSES; ++c) {
        float part = p0 * Wc[(f + 0) * N_CLASSES + c] + p1 * Wc[(f + 1) * N_CLASSES + c]
                   + p2 * Wc[(f + 2) * N_CLASSES + c] + p3 * Wc[(f + 3) * N_CLASSES + c];
        for (int s = 32; s > 0; s >>= 1) part += __shfl_down(part, s);
        if (lane == 0) logits[c] = part + bc[c];
    }
    __syncthreads();
    if (lane == 0) {
        float mx = logits[0];
        for (int c = 1; c < N_CLASSES; ++c) mx = fmaxf(mx, logits[c]);
        float se = 0.f;
        for (int c = 0; c < N_CLASSES; ++c) se += expf(logits[c] - mx);
        float lse = mx + logf(se);
        for (int c = 0; c < N_CLASSES; ++c) {
            out[g * N_CLASSES + c] = logits[c];
            out[N_GRAPHS * N_CLASSES + g * N_CLASSES + c] = logits[c] - lse;
        }
    }
}

// ---------------- launch ----------------
extern "C" void kernel_launch(void* const* d_in, const int* in_sizes, int n_in,
                              void* d_out, int out_size, void* d_ws, size_t ws_size,
                              hipStream_t stream) {
    const float* x    = (const float*)d_in[0];
    const int*   ei   = (const int*)d_in[1];
    const int*   src  = ei;
    const int*   dst  = ei + N_EDGES;
    const int*   batch= (const int*)d_in[2];
    const float* W1 = (const float*)d_in[3]; const float* b1 = (const float*)d_in[4];
    const float* W2 = (const float*)d_in[5]; const float* b2 = (const float*)d_in[6];
    const float* W3 = (const float*)d_in[7]; const float* b3 = (const float*)d_in[8];
    const float* Wc = (const float*)d_in[9]; const float* bc = (const float*)d_in[10];
    float* out = (float*)d_out;

    char* ws = (char*)d_ws;
    size_t off = 0;
    auto alloc = [&](size_t bytes) -> char* {
        char* p = ws + off;
        off = (off + bytes + 255) & ~(size_t)255;
        return p;
    };
    // ---- zeroed region (one memset) ----
    int*      deg     = (int*)alloc(N_NODES * 4);
    int*      fill    = (int*)alloc(N_NODES * 4);
    int*      counts  = (int*)alloc(N_GRAPHS * 4);
    float*    pooled  = (float*)alloc(N_GRAPHS * DIM * 4);
    unsigned* csr     = (unsigned*)alloc((size_t)CSR_CAP * 4);  // pad slots must be 0
    size_t    zero_bytes = off;
    // ---- uninitialized scratch ----
    float*  dinv    = (float*)alloc(N_NODES * 4);
    int*    pdeg    = (int*)alloc(N_NODES * 4);
    int*    row_ptr = (int*)alloc((N_NODES + 1) * 4);
    ushort* Wt1     = (ushort*)alloc(65536 * 2);
    ushort* Wt2     = (ushort*)alloc(65536 * 2);
    ushort* Wt3     = (ushort*)alloc(65536 * 2);
    ushort* xb      = (ushort*)alloc((size_t)N_NODES * DIM * 2);
    ushort* h1      = (ushort*)alloc((size_t)N_NODES * DIM * 2);
    unsigned char* h8 = (unsigned char*)alloc((size_t)2 * CHUNK);

    hipMemsetAsync(d_ws, 0, zero_bytes, stream);

    k_convert_x<<<(N_NODES * DIM / 4 + 255) / 256, 256, 0, stream>>>(x, xb, N_NODES * DIM / 4);
    k_wt<<<256, 256, 0, stream>>>(W1, Wt1);
    k_wt<<<256, 256, 0, stream>>>(W2, Wt2);
    k_wt<<<256, 256, 0, stream>>>(W3, Wt3);
    k_deg<<<(N_EDGES + 255) / 256, 256, 0, stream>>>(dst, deg);
    k_counts<<<(N_NODES + 255) / 256, 256, 0, stream>>>(batch, counts);
    k_dinv_pdeg<<<(N_NODES + 255) / 256, 256, 0, stream>>>(deg, dinv, pdeg);
    k_scan<<<1, 1024, 0, stream>>>(pdeg, row_ptr, N_NODES);
    k_self<<<(N_NODES + 255) / 256, 256, 0, stream>>>(row_ptr, fill, dinv, csr);
    k_fill<<<(N_EDGES + 255) / 256, 256, 0, stream>>>(src, dst, row_ptr, fill, dinv, csr);

    const int agg_grid = (N_NODES + 3) / 4;

    // conv1: h1 = relu(agg(xb @ W1) + b1)
    k_gemm<<<N_NODES / 16, 256, 0, stream>>>(xb, Wt1, h8);
    for (int p = 0; p < 2; ++p)
        k_agg<<<agg_grid, 256, 0, stream>>>(h8, row_ptr, csr, b1,
                                            nullptr, h1, nullptr, nullptr, 0, p);
    // conv2: xb = relu(h1 + agg(h1 @ W2) + b2)
    k_gemm<<<N_NODES / 16, 256, 0, stream>>>(h1, Wt2, h8);
    for (int p = 0; p < 2; ++p)
        k_agg<<<agg_grid, 256, 0, stream>>>(h8, row_ptr, csr, b2,
                                            h1, xb, nullptr, nullptr, 1, p);
    // conv3: pooled += agg(xb @ W3) + b3
    k_gemm<<<N_NODES / 16, 256, 0, stream>>>(xb, Wt3, h8);
    for (int p = 0; p < 2; ++p)
        k_agg<<<agg_grid, 256, 0, stream>>>(h8, row_ptr, csr, b3,
                                            nullptr, nullptr, pooled, batch, 2, p);

    k_final<<<N_GRAPHS, 64, 0, stream>>>(pooled, counts, Wc, bc, out);
}